// Round 5
// baseline (228.234 us; speedup 1.0000x reference)
//
#include <hip/hip_runtime.h>

#define B 8
#define C 256
#define HW 16384
#define NSEG 256
#define NBLK (B * C)     // 2048 main-kernel blocks
#define NCH 32           // chunks per batch for parallel prep
#define CHUNK (HW / NCH) // 512 pixels

// ws layout:
//   [0, 262144)        : int    hist[B][NCH][NSEG]      256 KiB
//   [262144, 393216)   : u8     ids8[B][HW]             128 KiB
//   [393216, 401408)   : int    starts[B][NSEG]           8 KiB
//   [401408, 663552)   : u16    permt[B][HW] (bit-transposed) 256 KiB
//   [663552, 679936)   : double partials[NBLK]           16 KiB

typedef unsigned short ushort8 __attribute__((ext_vector_type(8)));

__device__ __forceinline__ float sigmoidf(float x) {
    return 1.0f / (1.0f + __expf(-x));
}

// ---------------- prep stage 1: per-chunk histograms + u8 ids ----------------
__global__ __launch_bounds__(256) void hist_kernel(const float* __restrict__ mask,
                                                   int* __restrict__ hist,
                                                   unsigned char* __restrict__ ids8) {
    __shared__ int h[NSEG];
    const int blk = blockIdx.x;          // b*NCH + ch
    const int b = blk >> 5, ch = blk & 31;
    const int t = threadIdx.x;
    h[t] = 0;
    __syncthreads();

    const float2* m2 = (const float2*)(mask + (size_t)b * HW + ch * CHUNK);
    uchar2* o2 = (uchar2*)(ids8 + (size_t)b * HW + ch * CHUNK);
    float2 v = m2[t];                    // 256 threads x 2 px = 512 px
    int i0 = (int)v.x, i1 = (int)v.y;
    o2[t] = make_uchar2((unsigned char)i0, (unsigned char)i1);
    atomicAdd(&h[i0], 1);
    atomicAdd(&h[i1], 1);
    __syncthreads();
    hist[blk * NSEG + t] = h[t];
}

// ---------------- prep stage 2: scan + position assignment ----------------
// Positions within a segment may be assigned in any order (S,Q are sums).
__global__ __launch_bounds__(256) void assign_kernel(const unsigned char* __restrict__ ids8,
                                                     const int* __restrict__ hist,
                                                     int* __restrict__ starts_g,
                                                     unsigned short* __restrict__ permt) {
    __shared__ int sc[NSEG];
    __shared__ int cnt[NSEG];
    __shared__ int off[NSEG];
    const int blk = blockIdx.x;
    const int b = blk >> 5, ch = blk & 31;
    const int t = threadIdx.x;

    // total count per segment + prefix over earlier chunks
    int tot = 0, pre = 0;
    for (int c2 = 0; c2 < NCH; ++c2) {
        int v = hist[((b << 5) + c2) * NSEG + t];
        tot += v;
        if (c2 < ch) pre += v;
    }
    cnt[t] = tot;
    sc[t] = tot;
    __syncthreads();
    // Hillis-Steele inclusive scan over 256 segments
    for (int o = 1; o < NSEG; o <<= 1) {
        int v = (t >= o) ? sc[t - o] : 0;
        __syncthreads();
        sc[t] += v;
        __syncthreads();
    }
    int st = sc[t] - cnt[t];             // exclusive scan = segment start
    off[t] = st + pre;                   // this chunk's write cursor
    if (ch == 0) starts_g[b * NSEG + t] = st;
    __syncthreads();

    const unsigned char* idc = ids8 + (size_t)b * HW + ch * CHUNK;
    for (int j = 0; j < CHUNK / 256; ++j) {     // 2 iterations
        int pi = j * 256 + t;
        int id = idc[pi];
        int pos = atomicAdd(&off[id], 1);
        int p = ch * CHUNK + pi;
        // bit-transpose pos [w:2|l:6|j4:3|r:3] -> sidx [w:2|j4:3|l:6|r:3]
        // so main_kernel's per-wave ushort8 reads are fully coalesced.
        int sidx = (pos & ~4095) | (((pos >> 3) & 7) << 9) | (((pos >> 6) & 63) << 3) | (pos & 7);
        permt[(size_t)b * HW + sidx] = (unsigned short)p;
    }
}

// ---------------- main: stage x row in LDS, gather in sorted order ----------------
__global__ __launch_bounds__(256) void main_kernel(const float* __restrict__ x,
                                                   const unsigned short* __restrict__ permt,
                                                   const int* __restrict__ starts_g,
                                                   double* __restrict__ partials) {
    __shared__ float xs[HW];            // 64 KiB: the (b,c) row, linear
    __shared__ int st[NSEG + 1];
    __shared__ float bS[NSEG];
    __shared__ float bQ[NSEG];
    __shared__ double wsum[4];

    const int bid = blockIdx.x;          // = b*C + c = row index
    const int b = bid >> 8;
    const int t = threadIdx.x;

    // async stage: 16 iters x 256 lanes x 16 B = 64 KiB, linear dest
    const float* xrow = x + (size_t)bid * HW;
    for (int j = 0; j < 16; ++j) {
        int o = j * 1024 + t * 4;
        __builtin_amdgcn_global_load_lds(
            (const __attribute__((address_space(1))) void*)(xrow + o),
            (__attribute__((address_space(3))) void*)(xs + o), 16, 0, 0);
    }

    bS[t] = 0.0f;
    bQ[t] = 0.0f;
    st[t] = starts_g[b * NSEG + t];
    if (t == 0) st[NSEG] = HW;
    __syncthreads();   // drains vmcnt -> xs ready

    // thread t owns sorted positions [64t, 64t+64)
    int pos = t * 64;
    int lo = 0, hi = NSEG + 1;
    while (hi - lo > 1) {                // find s: st[s] <= pos < st[s+1]
        int mid = (lo + hi) >> 1;
        if (st[mid] <= pos) lo = mid; else hi = mid;
    }
    int s = lo;
    int nxt = st[s + 1];

    const ushort8* pr = (const ushort8*)(permt + (size_t)b * HW);
    const int w = t >> 6, l = t & 63;
    float S = 0.0f, Q = 0.0f;
    for (int j4 = 0; j4 < 8; ++j4) {
        // coalesced: lane l reads 16B at (w*4096 + j4*512 + l*8) ushorts
        ushort8 pp = pr[(w << 9) + (j4 << 6) + l];
        #pragma unroll
        for (int k = 0; k < 8; ++k) {
            int p = pp[k];
            float e = sigmoidf(xs[p]);
            if (pos >= nxt) {            // crossed a segment boundary: flush
                atomicAdd(&bS[s], S);
                atomicAdd(&bQ[s], Q);
                S = 0.0f; Q = 0.0f;
                do { ++s; } while (st[s + 1] <= pos);
                nxt = st[s + 1];
            }
            S += e;
            Q += e * e;
            ++pos;
        }
    }
    atomicAdd(&bS[s], S);
    atomicAdd(&bQ[s], Q);
    __syncthreads();

    // segment t combine (skip background 255 and empty segments)
    double p = 0.0;
    if (t < NSEG - 1) {
        int n = st[t + 1] - st[t];
        if (n > 0) {
            double Sd = (double)bS[t], Qd = (double)bQ[t];
            p = Qd - Sd * Sd / (double)n;
        }
    }
    #pragma unroll
    for (int o = 32; o > 0; o >>= 1) p += __shfl_down(p, o);
    const int lane = t & 63, wv = t >> 6;
    if (lane == 0) wsum[wv] = p;
    __syncthreads();
    if (t == 0) partials[bid] = wsum[0] + wsum[1] + wsum[2] + wsum[3];
}

__global__ __launch_bounds__(256) void final_kernel(const double* __restrict__ partials,
                                                    float* __restrict__ out) {
    __shared__ double wsum[4];
    const int t = threadIdx.x;
    double p = 0.0;
    #pragma unroll
    for (int j = 0; j < NBLK / 256; ++j) p += partials[j * 256 + t];
    #pragma unroll
    for (int o = 32; o > 0; o >>= 1) p += __shfl_down(p, o);
    const int lane = t & 63, w = t >> 6;
    if (lane == 0) wsum[w] = p;
    __syncthreads();
    if (t == 0) {
        double total = wsum[0] + wsum[1] + wsum[2] + wsum[3];
        out[0] = (float)(total / (double)((size_t)B * C * HW));
    }
}

extern "C" void kernel_launch(void* const* d_in, const int* in_sizes, int n_in,
                              void* d_out, int out_size, void* d_ws, size_t ws_size,
                              hipStream_t stream) {
    const float* x = (const float*)d_in[0];
    const float* mask = (const float*)d_in[1];
    float* out = (float*)d_out;

    char* ws = (char*)d_ws;
    int* hist = (int*)ws;                                      // 256 KiB
    unsigned char* ids8 = (unsigned char*)(ws + 262144);       // 128 KiB
    int* starts = (int*)(ws + 393216);                         //   8 KiB
    unsigned short* permt = (unsigned short*)(ws + 401408);    // 256 KiB
    double* partials = (double*)(ws + 663552);                 //  16 KiB

    hist_kernel<<<B * NCH, 256, 0, stream>>>(mask, hist, ids8);
    assign_kernel<<<B * NCH, 256, 0, stream>>>(ids8, hist, starts, permt);
    main_kernel<<<NBLK, 256, 0, stream>>>(x, permt, starts, partials);
    final_kernel<<<1, 256, 0, stream>>>(partials, out);
}